// Round 13
// baseline (72.946 us; speedup 1.0000x reference)
//
#include <hip/hip_runtime.h>
#include <math.h>

// N=100000, D=64, B=4096, W=10, L=8, M=128, T=64
constexpr int D_ = 64;
constexpr int B_ = 4096;
constexpr int W_ = 10;
constexpr int L_ = 8;
constexpr int M_ = 128;
constexpr int T_ = 64;
constexpr int NWALK = B_ * W_;   // 40960 walkers
constexpr int NPAIR = NWALK / 2; // 20480 walker pairs

// R12 (53.3us verified) with TWO walkers per 8-lane group (ILP pairing).
// Each thread carries two independent walkers; the serial S/C relay chains
// of the pair interleave inside one wave, filling the dependent-add latency
// bubbles that 5 waves/SIMD couldn't hide (VALUBusy 66%). Total issue count
// is unchanged (still 8 lanes per walker); grid halves to 2560 x 64-thread
// blocks (1 wave each, 10 waves/CU uniform). PER-WALKER ARITHMETIC IS
// BYTE-IDENTICAL TO R12: same ops, same order, same lane placement --
//  - S (softmax-sum) / C (CDF) folds: exact sequential relays (dpp
//    row_shr:1 handoff); the reference's 21M cdf compares sit at ~5e-8
//    margins -- never reorder these.
//  - precise expf and IEEE divides on the sampling path.
//  - fast cos + commutative butterfly trees on the restart side only
//    (validated accepted-risk class, 4 green rounds).
//  - in-register selection replaces end-of-step dependent gathers.
__device__ __forceinline__ float dpp_shr1(float x) {
    int xi = __builtin_amdgcn_update_dpp(0, __float_as_int(x), 0x111, 0xF, 0xF, true);
    return __int_as_float(xi);
}
template <int CTRL>
__device__ __forceinline__ float dpp_f(float x) {   // quad_perm lane permute
    return __int_as_float(__builtin_amdgcn_update_dpp(0, __float_as_int(x), CTRL, 0xF, 0xF, true));
}
template <int CTRL>
__device__ __forceinline__ int dpp_i(int x) {
    return __builtin_amdgcn_update_dpp(0, x, CTRL, 0xF, 0xF, true);
}
template <int PAT>
__device__ __forceinline__ float swz_f(float x) {
    return __int_as_float(__builtin_amdgcn_ds_swizzle(__float_as_int(x), PAT));
}
template <int PAT>
__device__ __forceinline__ int swz_i(int x) {
    return __builtin_amdgcn_ds_swizzle(x, PAT);
}
constexpr int XOR1 = 0xB1;   // quad_perm [1,0,3,2]
constexpr int XOR2 = 0x4E;   // quad_perm [2,3,0,1]
constexpr float INV2PI = 0.15915494309189535f;

__global__ __launch_bounds__(64) void walk_kernel(
    const int*   __restrict__ nbr_ids,      // [N,D]
    const float* __restrict__ nbr_time,     // [N,D]
    const int*   __restrict__ nbr_cnt,      // [N]
    const int*   __restrict__ start_nodes,  // [B]
    const float* __restrict__ start_times,  // [B]
    const float* __restrict__ mem,          // [N,M]
    const float* __restrict__ time_w,       // [T]
    const float* __restrict__ time_b,       // [T]
    const float* __restrict__ restart_w,    // [M+T]
    const float* __restrict__ restart_b,    // [1]
    const float* __restrict__ rand_restart, // [L,B,W]
    const float* __restrict__ rand_neighbor,// [L,B,W]
    float* __restrict__ out_nodes,          // [B,W,L+1] (as f32)
    float* __restrict__ out_times,          // [B,W,L+1]
    float* __restrict__ out_probs)          // [B,W,L]
{
    const int tid = blockIdx.x * 64 + threadIdx.x;
    const int pr  = tid >> 3;          // pair id (grid exact: no bounds check)
    const int r   = tid & 7;           // lane-in-group
    const int g0  = pr * 2;
    const int g1  = g0 + 1;
    const int b0  = g0 / W_;
    const int b1  = g1 / W_;

    const int   sn0 = start_nodes[b0]; const float st0 = start_times[b0];
    const int   sn1 = start_nodes[b1]; const float st1 = start_times[b1];
    int   cur_n0 = sn0, cur_n1 = sn1;
    float cur_t0 = st0, cur_t1 = st1;

    float* __restrict__ on0 = out_nodes + (size_t)g0 * (L_ + 1);
    float* __restrict__ ot0 = out_times + (size_t)g0 * (L_ + 1);
    float* __restrict__ op0 = out_probs + (size_t)g0 * L_;
    float* __restrict__ on1 = out_nodes + (size_t)g1 * (L_ + 1);
    float* __restrict__ ot1 = out_times + (size_t)g1 * (L_ + 1);
    float* __restrict__ op1 = out_probs + (size_t)g1 * L_;
    if (r == 0) {
        on0[0] = (float)sn0; ot0[0] = st0;
        on1[0] = (float)sn1; ot1[0] = st1;
    }

    const float rb = restart_b[0];

    // loop-invariant chunks, shared by both walkers (same lane role)
    float wv[16];
    {
        const float4* p = reinterpret_cast<const float4*>(restart_w) + r * 4;
        float4 v0 = p[0], v1 = p[1], v2 = p[2], v3 = p[3];
        *(float4*)&wv[0] = v0; *(float4*)&wv[4] = v1;
        *(float4*)&wv[8] = v2; *(float4*)&wv[12] = v3;
    }
    float tw[8], tb[8], rw2[8];
    {
        const float4* ptw = reinterpret_cast<const float4*>(time_w + 8 * r);
        const float4* ptb = reinterpret_cast<const float4*>(time_b + 8 * r);
        const float4* prw = reinterpret_cast<const float4*>(restart_w + M_ + 8 * r);
        *(float4*)&tw[0] = ptw[0]; *(float4*)&tw[4] = ptw[1];
        *(float4*)&tb[0] = ptb[0]; *(float4*)&tb[4] = ptb[1];
        *(float4*)&rw2[0] = prw[0]; *(float4*)&rw2[4] = prw[1];
    }

    for (int l = 0; l < L_; ++l) {
        // ---------- all step loads for BOTH walkers issue up-front ----------
        const float r_re0 = rand_restart [(size_t)l * NWALK + g0];
        const float r_nb0 = rand_neighbor[(size_t)l * NWALK + g0];
        const float r_re1 = rand_restart [(size_t)l * NWALK + g1];
        const float r_nb1 = rand_neighbor[(size_t)l * NWALK + g1];
        float mv0[16], mv1[16];
        {
            const float4* p0 = reinterpret_cast<const float4*>(mem + (size_t)cur_n0 * M_) + r * 4;
            const float4* p1 = reinterpret_cast<const float4*>(mem + (size_t)cur_n1 * M_) + r * 4;
            float4 a0 = p0[0], a1 = p0[1], a2 = p0[2], a3 = p0[3];
            float4 c0 = p1[0], c1 = p1[1], c2 = p1[2], c3 = p1[3];
            *(float4*)&mv0[0] = a0; *(float4*)&mv0[4] = a1;
            *(float4*)&mv0[8] = a2; *(float4*)&mv0[12] = a3;
            *(float4*)&mv1[0] = c0; *(float4*)&mv1[4] = c1;
            *(float4*)&mv1[8] = c2; *(float4*)&mv1[12] = c3;
        }
        float tv0[8], tv1[8];
        {
            const float4* p0 = reinterpret_cast<const float4*>(nbr_time + (size_t)cur_n0 * D_) + r * 2;
            const float4* p1 = reinterpret_cast<const float4*>(nbr_time + (size_t)cur_n1 * D_) + r * 2;
            float4 a0 = p0[0], a1 = p0[1];
            float4 c0 = p1[0], c1 = p1[1];
            *(float4*)&tv0[0] = a0; *(float4*)&tv0[4] = a1;
            *(float4*)&tv1[0] = c0; *(float4*)&tv1[4] = c1;
        }
        int iv0[8], iv1[8];
        {
            const int4* p0 = reinterpret_cast<const int4*>(nbr_ids + (size_t)cur_n0 * D_) + r * 2;
            const int4* p1 = reinterpret_cast<const int4*>(nbr_ids + (size_t)cur_n1 * D_) + r * 2;
            int4 a0 = p0[0], a1 = p0[1];
            int4 c0 = p1[0], c1 = p1[1];
            *(int4*)&iv0[0] = a0; *(int4*)&iv0[4] = a1;
            *(int4*)&iv1[0] = c0; *(int4*)&iv1[4] = c1;
        }
        const int cnt0 = nbr_cnt[cur_n0];
        const int cnt1 = nbr_cnt[cur_n1];

        // ---------- fast time-encoder terms (restart side only) ----------
        float cosv0[8], cosv1[8];
        #pragma unroll
        for (int i = 0; i < 8; ++i) {
            const float x0 = cur_t0 * tw[i] + tb[i];
            const float x1 = cur_t1 * tw[i] + tb[i];
            cosv0[i] = __builtin_amdgcn_cosf(__builtin_amdgcn_fractf(x0 * INV2PI));
            cosv1[i] = __builtin_amdgcn_cosf(__builtin_amdgcn_fractf(x1 * INV2PI));
        }

        // ---------- neighbor scores + max trees (per walker, exact) ----------
        float e0[8], e1[8];
        float lmx0 = -1e9f, lmx1 = -1e9f;
        #pragma unroll
        for (int i = 0; i < 8; ++i) {
            const float tj0 = tv0[i];
            const bool  v0  = (tj0 < cur_t0) && ((8 * r + i) < cnt0);
            const float s0  = v0 ? (tj0 - cur_t0) / 0.1f : -1e9f;   // true division
            e0[i] = s0;
            lmx0 = fmaxf(lmx0, s0);
            const float tj1 = tv1[i];
            const bool  v1  = (tj1 < cur_t1) && ((8 * r + i) < cnt1);
            const float s1  = v1 ? (tj1 - cur_t1) / 0.1f : -1e9f;
            e1[i] = s1;
            lmx1 = fmaxf(lmx1, s1);
        }
        lmx0 = fmaxf(lmx0, dpp_f<XOR1>(lmx0));
        lmx1 = fmaxf(lmx1, dpp_f<XOR1>(lmx1));
        lmx0 = fmaxf(lmx0, dpp_f<XOR2>(lmx0));
        lmx1 = fmaxf(lmx1, dpp_f<XOR2>(lmx1));
        lmx0 = fmaxf(lmx0, swz_f<0x101F>(lmx0));
        lmx1 = fmaxf(lmx1, swz_f<0x101F>(lmx1));
        const bool hv0 = (lmx0 != -1e9f);
        const bool hv1 = (lmx1 != -1e9f);

        #pragma unroll
        for (int i = 0; i < 8; ++i) {
            e0[i] = expf(e0[i] - lmx0);   // EXACT (cdf path)
            e1[i] = expf(e1[i] - lmx1);
        }

        // ---------- restart logits: full-lane TREE reductions ----------
        float tA0 = 0.f, tA1 = 0.f;
        #pragma unroll
        for (int i = 0; i < 16; ++i) { tA0 += mv0[i] * wv[i]; tA1 += mv1[i] * wv[i]; }
        tA0 += dpp_f<XOR1>(tA0);  tA1 += dpp_f<XOR1>(tA1);
        tA0 += dpp_f<XOR2>(tA0);  tA1 += dpp_f<XOR2>(tA1);
        tA0 += swz_f<0x101F>(tA0); tA1 += swz_f<0x101F>(tA1);
        float tB0 = 0.f, tB1 = 0.f;
        #pragma unroll
        for (int i = 0; i < 8; ++i) { tB0 += cosv0[i] * rw2[i]; tB1 += cosv1[i] * rw2[i]; }
        tB0 += dpp_f<XOR1>(tB0);  tB1 += dpp_f<XOR1>(tB1);
        tB0 += dpp_f<XOR2>(tB0);  tB1 += dpp_f<XOR2>(tB1);
        tB0 += swz_f<0x101F>(tB0); tB1 += swz_f<0x101F>(tB1);

        const float logits0 = tA0 + tB0 + rb;
        const float logits1 = tA1 + tB1 + rb;
        const float p0 = 1.f / (1.f + expf(-logits0));
        const float p1 = 1.f / (1.f + expf(-logits1));
        const bool restart0 = r_re0 < p0;
        const bool restart1 = r_re1 < p1;

        // ---------- softmax sums: fused EXACT sequential relays ----------
        // Two independent chains advance per hop; per-walker order unchanged.
        float runS0 = 0.f, runS1 = 0.f;
        #pragma unroll
        for (int rr = 0; rr < 8; ++rr) {
            const float pS0 = dpp_shr1(runS0);
            const float pS1 = dpp_shr1(runS1);
            float tS0 = pS0, tS1 = pS1;
            #pragma unroll
            for (int i = 0; i < 8; ++i) { tS0 += e0[i]; tS1 += e1[i]; }
            const bool m = (r == rr);
            runS0 = m ? tS0 : runS0;
            runS1 = m ? tS1 : runS1;
        }
        const float ssum0 = swz_f<0x00F8>(runS0);
        const float ssum1 = swz_f<0x00F8>(runS1);

        // exact elementwise divisions (identical per walker)
        float q0[8], q1[8];
        #pragma unroll
        for (int i = 0; i < 8; ++i) { q0[i] = e0[i] / ssum0; q1[i] = e1[i] / ssum1; }

        // ---------- CDF relays (adds only) fused + parallel counts ----------
        float pfx0[8], pfx1[8];
        float runC0 = 0.f, runC1 = 0.f;
        #pragma unroll
        for (int rr = 0; rr < 8; ++rr) {
            const float pC0 = dpp_shr1(runC0);
            const float pC1 = dpp_shr1(runC1);
            if (r == rr) {
                if (rr > 0) { runC0 = pC0; runC1 = pC1; }
                #pragma unroll
                for (int i = 0; i < 8; ++i) {
                    runC0 += q0[i]; pfx0[i] = runC0;   // exact j-order adds
                    runC1 += q1[i]; pfx1[i] = runC1;
                }
            }
        }
        int cloc0 = 0, cloc1 = 0;
        #pragma unroll
        for (int i = 0; i < 8; ++i) {
            cloc0 += (pfx0[i] < r_nb0) ? 1 : 0;
            cloc1 += (pfx1[i] < r_nb1) ? 1 : 0;
        }
        int idx0 = cloc0, idx1 = cloc1;   // integer tree: exact
        idx0 += dpp_i<XOR1>(idx0);  idx1 += dpp_i<XOR1>(idx1);
        idx0 += dpp_i<XOR2>(idx0);  idx1 += dpp_i<XOR2>(idx1);
        idx0 += swz_i<0x101F>(idx0); idx1 += swz_i<0x101F>(idx1);
        if (idx0 > D_ - 1) idx0 = D_ - 1;
        if (idx1 > D_ - 1) idx1 = D_ - 1;

        // ---------- in-register selection (no dependent gathers) ----------
        const int owner0 = idx0 >> 3, j0 = idx0 & 7;
        const int owner1 = idx1 >> 3, j1 = idx1 & 7;
        float cand_t0 = tv0[0], cand_t1 = tv1[0];
        int   cand_i0 = iv0[0], cand_i1 = iv1[0];
        #pragma unroll
        for (int k = 1; k < 8; ++k) {
            cand_t0 = (j0 == k) ? tv0[k] : cand_t0;
            cand_i0 = (j0 == k) ? iv0[k] : cand_i0;
            cand_t1 = (j1 == k) ? tv1[k] : cand_t1;
            cand_i1 = (j1 == k) ? iv1[k] : cand_i1;
        }
        const float sel_t0  = __shfl(cand_t0, owner0, 8);
        const int   sel_id0 = __shfl(cand_i0, owner0, 8);
        const float sel_t1  = __shfl(cand_t1, owner1, 8);
        const int   sel_id1 = __shfl(cand_i1, owner1, 8);

        const int   step_n0 = hv0 ? sel_id0 : cur_n0;
        const float step_t0 = hv0 ? sel_t0  : cur_t0;
        const int   step_n1 = hv1 ? sel_id1 : cur_n1;
        const float step_t1 = hv1 ? sel_t1  : cur_t1;
        cur_n0 = restart0 ? sn0 : step_n0;
        cur_t0 = restart0 ? st0 : step_t0;
        cur_n1 = restart1 ? sn1 : step_n1;
        cur_t1 = restart1 ? st1 : step_t1;

        if (r == 0) {
            on0[l + 1] = (float)cur_n0;
            ot0[l + 1] = cur_t0;
            op0[l]     = p0;
            on1[l + 1] = (float)cur_n1;
            ot1[l + 1] = cur_t1;
            op1[l]     = p1;
        }
    }
}

extern "C" void kernel_launch(void* const* d_in, const int* in_sizes, int n_in,
                              void* d_out, int out_size, void* d_ws, size_t ws_size,
                              hipStream_t stream) {
    const int*   nbr_ids       = (const int*)  d_in[0];
    const float* nbr_time      = (const float*)d_in[1];
    const int*   nbr_cnt       = (const int*)  d_in[2];
    const int*   start_nodes   = (const int*)  d_in[3];
    const float* start_times   = (const float*)d_in[4];
    const float* memst         = (const float*)d_in[5];
    const float* time_w        = (const float*)d_in[6];
    const float* time_b        = (const float*)d_in[7];
    const float* restart_w     = (const float*)d_in[8];
    const float* restart_b     = (const float*)d_in[9];
    const float* rand_restart  = (const float*)d_in[10];
    const float* rand_neighbor = (const float*)d_in[11];

    float* out_nodes = (float*)d_out;
    float* out_times = out_nodes + (size_t)B_ * W_ * (L_ + 1);
    float* out_probs = out_times + (size_t)B_ * W_ * (L_ + 1);

    const int threads = 64;
    const int blocks  = (NPAIR * 8) / threads;   // 2560
    hipLaunchKernelGGL(walk_kernel, dim3(blocks), dim3(threads), 0, stream,
                       nbr_ids, nbr_time, nbr_cnt, start_nodes, start_times,
                       memst, time_w, time_b, restart_w, restart_b,
                       rand_restart, rand_neighbor,
                       out_nodes, out_times, out_probs);
}

// Round 14
// 53.222 us; speedup vs baseline: 1.3706x; 1.3706x over previous
//
#include <hip/hip_runtime.h>
#include <math.h>

// N=100000, D=64, B=4096, W=10, L=8, M=128, T=64
constexpr int D_ = 64;
constexpr int B_ = 4096;
constexpr int W_ = 10;
constexpr int L_ = 8;
constexpr int M_ = 128;
constexpr int T_ = 64;
constexpr int NWALK = B_ * W_;   // 40960 walkers
constexpr int K_ = 8;            // lanes per walker (optimum of K-sweep 1/4/8/16)

// FINAL (R10/R12 state, 53.25us verified twice): 8 lanes per walker.
// Session ladder: 206 (scalar) -> 82 (8-lane relay) -> 75.5 (slim CDF) ->
// 73.6 (loads up-front + in-reg selection) -> 69.1 (dpp handoff + fused
// relays) -> 59.0 (A/B tree) -> 53.3 (fast cos + dpp quad_perm trees).
// Measured dead ends: K=4 (92), K=16 (59.6), block-fold (124), ILP-pair (72.9).
//  - All step loads issue up-front; in-register selection replaces the
//    end-of-step dependent gathers (sel_id/sel_t from resident iv/tv regs).
//  - cosf -> v_cos_f32(v_fract(x/2pi)) on the restart side only (~100x
//    margin headroom there; sampling side untouched).
//  - A/B restart-logit dots: lane-local fmac chains + commutative xor
//    butterfly (dpp quad_perm for xor1/2, ds_swizzle for xor4).
//  - S (softmax-sum) and C (CDF) folds are BYTE-IDENTICAL sequential
//    relays (dpp row_shr:1 handoff, masked hops): the reference's 21M cdf
//    compares sit at ~5e-8 margins — these chains must never be reordered.
//  - q = e/ssum via IEEE divides; expf precise: both feed the cdf compares.
__device__ __forceinline__ float dpp_shr1(float x) {
    int xi = __builtin_amdgcn_update_dpp(0, __float_as_int(x), 0x111, 0xF, 0xF, true);
    return __int_as_float(xi);
}
template <int CTRL>
__device__ __forceinline__ float dpp_f(float x) {   // quad_perm lane permute
    return __int_as_float(__builtin_amdgcn_update_dpp(0, __float_as_int(x), CTRL, 0xF, 0xF, true));
}
template <int CTRL>
__device__ __forceinline__ int dpp_i(int x) {
    return __builtin_amdgcn_update_dpp(0, x, CTRL, 0xF, 0xF, true);
}
template <int PAT>
__device__ __forceinline__ float swz_f(float x) {
    return __int_as_float(__builtin_amdgcn_ds_swizzle(__float_as_int(x), PAT));
}
template <int PAT>
__device__ __forceinline__ int swz_i(int x) {
    return __builtin_amdgcn_ds_swizzle(x, PAT);
}
constexpr int XOR1 = 0xB1;   // quad_perm [1,0,3,2]
constexpr int XOR2 = 0x4E;   // quad_perm [2,3,0,1]
constexpr float INV2PI = 0.15915494309189535f;

__global__ __launch_bounds__(256) void walk_kernel(
    const int*   __restrict__ nbr_ids,      // [N,D]
    const float* __restrict__ nbr_time,     // [N,D]
    const int*   __restrict__ nbr_cnt,      // [N]
    const int*   __restrict__ start_nodes,  // [B]
    const float* __restrict__ start_times,  // [B]
    const float* __restrict__ mem,          // [N,M]
    const float* __restrict__ time_w,       // [T]
    const float* __restrict__ time_b,       // [T]
    const float* __restrict__ restart_w,    // [M+T]
    const float* __restrict__ restart_b,    // [1]
    const float* __restrict__ rand_restart, // [L,B,W]
    const float* __restrict__ rand_neighbor,// [L,B,W]
    float* __restrict__ out_nodes,          // [B,W,L+1] (as f32)
    float* __restrict__ out_times,          // [B,W,L+1]
    float* __restrict__ out_probs)          // [B,W,L]
{
    const int tid = blockIdx.x * blockDim.x + threadIdx.x;
    const int gid = tid >> 3;          // walker id
    const int r   = tid & 7;           // lane-in-group
    if (gid >= NWALK) return;
    const int b = gid / W_;

    const int   sn = start_nodes[b];
    const float st = start_times[b];
    int   cur_n = sn;
    float cur_t = st;

    float* __restrict__ on = out_nodes + (size_t)gid * (L_ + 1);
    float* __restrict__ ot = out_times + (size_t)gid * (L_ + 1);
    float* __restrict__ op = out_probs + (size_t)gid * L_;
    if (r == 0) { on[0] = (float)sn; ot[0] = st; }

    const float rb = restart_b[0];

    // loop-invariant chunks (lane r owns mem elems 16r.., time elems 8r..)
    float wv[16];
    {
        const float4* p = reinterpret_cast<const float4*>(restart_w) + r * 4;
        float4 v0 = p[0], v1 = p[1], v2 = p[2], v3 = p[3];
        *(float4*)&wv[0] = v0; *(float4*)&wv[4] = v1;
        *(float4*)&wv[8] = v2; *(float4*)&wv[12] = v3;
    }
    float tw[8], tb[8], rw2[8];
    {
        const float4* ptw = reinterpret_cast<const float4*>(time_w + 8 * r);
        const float4* ptb = reinterpret_cast<const float4*>(time_b + 8 * r);
        const float4* prw = reinterpret_cast<const float4*>(restart_w + M_ + 8 * r);
        *(float4*)&tw[0] = ptw[0]; *(float4*)&tw[4] = ptw[1];
        *(float4*)&tb[0] = ptb[0]; *(float4*)&tb[4] = ptb[1];
        *(float4*)&rw2[0] = prw[0]; *(float4*)&rw2[4] = prw[1];
    }

    for (int l = 0; l < L_; ++l) {
        // ---------- all step loads issue up-front ----------
        const float r_re = rand_restart [(size_t)l * NWALK + gid];
        const float r_nb = rand_neighbor[(size_t)l * NWALK + gid];
        const float* __restrict__ mrow    = mem      + (size_t)cur_n * M_;
        const float* __restrict__ nts_row = nbr_time + (size_t)cur_n * D_;
        const int*   __restrict__ ids_row = nbr_ids  + (size_t)cur_n * D_;
        float mv[16];
        {
            const float4* p = reinterpret_cast<const float4*>(mrow) + r * 4;
            float4 v0 = p[0], v1 = p[1], v2 = p[2], v3 = p[3];
            *(float4*)&mv[0] = v0; *(float4*)&mv[4] = v1;
            *(float4*)&mv[8] = v2; *(float4*)&mv[12] = v3;
        }
        float tv[8];
        {
            const float4* p = reinterpret_cast<const float4*>(nts_row) + r * 2;
            float4 v0 = p[0], v1 = p[1];
            *(float4*)&tv[0] = v0; *(float4*)&tv[4] = v1;
        }
        int iv[8];
        {
            const int4* p = reinterpret_cast<const int4*>(ids_row) + r * 2;
            int4 v0 = p[0], v1 = p[1];
            *(int4*)&iv[0] = v0; *(int4*)&iv[4] = v1;
        }
        const int cnt = nbr_cnt[cur_n];

        // ---------- fast time-encoder terms (restart side only) ----------
        // cos(x) = v_cos(fract(x/2pi)); |x|<6 so the reduction is sub-ulp.
        float cosv[8];
        #pragma unroll
        for (int i = 0; i < 8; ++i) {
            const float x = cur_t * tw[i] + tb[i];
            cosv[i] = __builtin_amdgcn_cosf(__builtin_amdgcn_fractf(x * INV2PI));
        }

        float e[8];
        float lmx = -1e9f;
        #pragma unroll
        for (int i = 0; i < 8; ++i) {
            const float tj = tv[i];
            const bool  v  = (tj < cur_t) && ((8 * r + i) < cnt);
            const float s  = v ? (tj - cur_t) / 0.1f : -1e9f;   // true division
            e[i] = s;
            lmx = fmaxf(lmx, s);
        }
        lmx = fmaxf(lmx, dpp_f<XOR1>(lmx));     // xor 1 (exact permute)
        lmx = fmaxf(lmx, dpp_f<XOR2>(lmx));     // xor 2
        lmx = fmaxf(lmx, swz_f<0x101F>(lmx));   // xor 4
        const bool hv = (lmx != -1e9f);

        #pragma unroll
        for (int i = 0; i < 8; ++i) e[i] = expf(e[i] - lmx);   // EXACT (cdf path)

        // ---------- restart logit: full-lane TREE reductions ----------
        float tA = 0.f;
        #pragma unroll
        for (int i = 0; i < 16; ++i) tA += mv[i] * wv[i];   // lane-local fmac chain
        tA += dpp_f<XOR1>(tA);
        tA += dpp_f<XOR2>(tA);
        tA += swz_f<0x101F>(tA);
        float tB = 0.f;
        #pragma unroll
        for (int i = 0; i < 8; ++i) tB += cosv[i] * rw2[i];
        tB += dpp_f<XOR1>(tB);
        tB += dpp_f<XOR2>(tB);
        tB += swz_f<0x101F>(tB);

        const float logits = tA + tB + rb;
        const float p = 1.f / (1.f + expf(-logits));
        const bool restart = r_re < p;

        // ---------- softmax sum: EXACT sequential relay (dpp handoff) ------
        float runS = 0.f;
        #pragma unroll
        for (int rr = 0; rr < 8; ++rr) {
            const float pS = dpp_shr1(runS);
            float tS = pS;
            #pragma unroll
            for (int i = 0; i < 8; ++i) tS += e[i];   // exact j-order adds
            runS = (r == rr) ? tS : runS;
        }
        const float ssum = swz_f<0x00F8>(runS);

        // exact elementwise divisions (identical to baseline)
        float q[8];
        #pragma unroll
        for (int i = 0; i < 8; ++i) q[i] = e[i] / ssum;

        // ---------- CDF relay (adds only, dpp handoff) + parallel count ----
        float pfx[8];
        float runC = 0.f;
        #pragma unroll
        for (int rr = 0; rr < 8; ++rr) {
            const float pC = dpp_shr1(runC);
            if (r == rr) {
                if (rr > 0) runC = pC;
                #pragma unroll
                for (int i = 0; i < 8; ++i) {
                    runC += q[i];          // exact j-order adds
                    pfx[i] = runC;
                }
            }
        }
        int cloc = 0;
        #pragma unroll
        for (int i = 0; i < 8; ++i) cloc += (pfx[i] < r_nb) ? 1 : 0;
        int idx = cloc;   // integer add associative: tree exact
        idx += dpp_i<XOR1>(idx);
        idx += dpp_i<XOR2>(idx);
        idx += swz_i<0x101F>(idx);
        if (idx > D_ - 1) idx = D_ - 1;

        // ---------- in-register selection (no dependent gathers) ----------
        const int owner = idx >> 3;
        const int j     = idx & 7;
        float cand_t = tv[0];
        int   cand_i = iv[0];
        #pragma unroll
        for (int k = 1; k < 8; ++k) {
            cand_t = (j == k) ? tv[k] : cand_t;
            cand_i = (j == k) ? iv[k] : cand_i;
        }
        const float sel_t  = __shfl(cand_t, owner, 8);
        const int   sel_id = __shfl(cand_i, owner, 8);

        const int   step_n = hv ? sel_id : cur_n;
        const float step_t = hv ? sel_t  : cur_t;
        cur_n = restart ? sn : step_n;
        cur_t = restart ? st : step_t;

        if (r == 0) {
            on[l + 1] = (float)cur_n;
            ot[l + 1] = cur_t;
            op[l]     = p;
        }
    }
}

extern "C" void kernel_launch(void* const* d_in, const int* in_sizes, int n_in,
                              void* d_out, int out_size, void* d_ws, size_t ws_size,
                              hipStream_t stream) {
    const int*   nbr_ids       = (const int*)  d_in[0];
    const float* nbr_time      = (const float*)d_in[1];
    const int*   nbr_cnt       = (const int*)  d_in[2];
    const int*   start_nodes   = (const int*)  d_in[3];
    const float* start_times   = (const float*)d_in[4];
    const float* memst         = (const float*)d_in[5];
    const float* time_w        = (const float*)d_in[6];
    const float* time_b        = (const float*)d_in[7];
    const float* restart_w     = (const float*)d_in[8];
    const float* restart_b     = (const float*)d_in[9];
    const float* rand_restart  = (const float*)d_in[10];
    const float* rand_neighbor = (const float*)d_in[11];

    float* out_nodes = (float*)d_out;
    float* out_times = out_nodes + (size_t)B_ * W_ * (L_ + 1);
    float* out_probs = out_times + (size_t)B_ * W_ * (L_ + 1);

    const int threads = 256;
    const int blocks  = (NWALK * K_ + threads - 1) / threads;   // 1280
    hipLaunchKernelGGL(walk_kernel, dim3(blocks), dim3(threads), 0, stream,
                       nbr_ids, nbr_time, nbr_cnt, start_nodes, start_times,
                       memst, time_w, time_b, restart_w, restart_b,
                       rand_restart, rand_neighbor,
                       out_nodes, out_times, out_probs);
}